// Round 1
// baseline (130.482 us; speedup 1.0000x reference)
//
#include <hip/hip_runtime.h>
#include <math.h>

#define BLOCK 256
#define COARSE 4
#define TILE (BLOCK * COARSE)   // 1024 elements per tile

__device__ __forceinline__ float sp(float x) {
    // stable softplus: log(1+e^x) = max(x,0) + log1p(exp(-|x|))
    return fmaxf(x, 0.0f) + log1pf(__expf(-fabsf(x)));
}

__global__ __launch_bounds__(BLOCK) void socnet_kernel(
    const float4* __restrict__ X,     // (N, L) of float4 (4 ch)
    const float*  __restrict__ SC,    // (N, 4)
    const float*  __restrict__ wi1, const float* __restrict__ bi1,
    const float*  __restrict__ wi2, const float* __restrict__ bi2,
    const float*  __restrict__ we1, const float* __restrict__ be1,
    const float*  __restrict__ we2, const float* __restrict__ be2,
    float4* __restrict__ Y, int L)
{
    const int n    = blockIdx.x;
    const int t    = threadIdx.x;
    const int lane = t & 63;
    const int wid  = t >> 6;

    const size_t rowoff = (size_t)n * (size_t)L;
    const float4* Xr = X + rowoff;
    float4*       Yr = Y + rowoff;

    // eta MLP weights (scalars, broadcast via cache)
    const float W10 = we1[0], W11 = we1[1], B1 = be1[0];
    const float W2  = we2[0], B2e = be2[0];

    // per-row scalars
    const float Q    = SC[n * 4 + 0];
    const float eta0 = SC[n * 4 + 1];
    const float R    = SC[n * 4 + 2];
    const float S3   = SC[n * 4 + 3];
    const float inv  = eta0 / (3600.0f * Q);

    // soc_init from X[n,0,:] — computed redundantly by all threads (cached load)
    float4 x0 = Xr[0];
    float h0  = sp(wi1[0] * x0.y + wi1[1] * x0.z + wi1[2] * x0.w + wi1[3] * R + bi1[0]);
    const float soc = S3 * (1.0f + (wi2[0] * h0 + bi2[0]));

    __shared__ float4 s_obs0[BLOCK];       // each thread's first obs, for neighbor
    __shared__ float4 s_wsum[BLOCK / 64];  // per-wave scan totals

    float4 carry = make_float4(0.f, 0.f, 0.f, 0.f);  // block prefix across tiles

    const int ntiles = L / TILE;
    for (int tile = 0; tile < ntiles; ++tile) {
        const int base = tile * TILE + t * COARSE;  // first l owned by this thread

        // ---- load 4 consecutive X elements (64 B/thread, coalesced) ----
        float4 xv[COARSE];
        #pragma unroll
        for (int j = 0; j < COARSE; ++j) xv[j] = Xr[base + j];

        // ---- obs = (I, T, U, delta_eta); dy_dt ----
        float4 obs[COARSE];
        float  dy[COARSE];
        #pragma unroll
        for (int j = 0; j < COARSE; ++j) {
            const float I = xv[j].y, T = xv[j].z, U = xv[j].w;
            const float de = W2 * sp(W10 * I + W11 * T + B1) + B2e;
            obs[j] = make_float4(I, T, U, de);
            dy[j]  = inv * (1.0f + de) * I;
        }

        s_obs0[t] = obs[0];
        __syncthreads();  // (A)

        // obs at l = base+COARSE (next thread's first element)
        float4 obs4;
        if (t < BLOCK - 1) {
            obs4 = s_obs0[t + 1];
        } else {
            const int lnext = base + COARSE;  // == (tile+1)*TILE
            if (lnext < L) {
                float4 xn = Xr[lnext];
                const float I = xn.y, T = xn.z, U = xn.w;
                const float de = W2 * sp(W10 * I + W11 * T + B1) + B2e;
                obs4 = make_float4(I, T, U, de);
            } else {
                obs4 = obs[COARSE - 1];  // makes inc = 0 at l = L-1 (unused)
            }
        }

        // ---- inc[j] = (obs[j+1]-obs[j]) * dy[j]; local inclusive scan ----
        float4 loc[COARSE];
        float4 run = make_float4(0.f, 0.f, 0.f, 0.f);
        #pragma unroll
        for (int j = 0; j < COARSE; ++j) {
            const float4 nx = (j < COARSE - 1) ? obs[j + 1] : obs4;
            run.x += (nx.x - obs[j].x) * dy[j];
            run.y += (nx.y - obs[j].y) * dy[j];
            run.z += (nx.z - obs[j].z) * dy[j];
            run.w += (nx.w - obs[j].w) * dy[j];
            loc[j] = run;
        }
        const float4 tot = run;

        // ---- wave-inclusive scan of per-thread totals (64 lanes!) ----
        float4 scn = tot;
        #pragma unroll
        for (int off = 1; off < 64; off <<= 1) {
            const float ox = __shfl_up(scn.x, off);
            const float oy = __shfl_up(scn.y, off);
            const float oz = __shfl_up(scn.z, off);
            const float ow = __shfl_up(scn.w, off);
            if (lane >= off) { scn.x += ox; scn.y += oy; scn.z += oz; scn.w += ow; }
        }
        if (lane == 63) s_wsum[wid] = scn;
        __syncthreads();  // (B)

        // exclusive prefix for this thread = carry + prev-wave totals + (scn - tot)
        float4 excl = carry;
        #pragma unroll
        for (int w = 0; w < BLOCK / 64; ++w) {
            if (w < wid) {
                excl.x += s_wsum[w].x; excl.y += s_wsum[w].y;
                excl.z += s_wsum[w].z; excl.w += s_wsum[w].w;
            }
        }
        excl.x += scn.x - tot.x;
        excl.y += scn.y - tot.y;
        excl.z += scn.z - tot.z;
        excl.w += scn.w - tot.w;

        // ---- write y[l+1] = soc + inclusive_prefix(inc)[l] ----
        #pragma unroll
        for (int j = 0; j < COARSE; ++j) {
            const int lo = base + j + 1;
            if (lo < L) {
                Yr[lo] = make_float4(soc + excl.x + loc[j].x,
                                     soc + excl.y + loc[j].y,
                                     soc + excl.z + loc[j].z,
                                     soc + excl.w + loc[j].w);
            }
        }

        // carry += block total
        #pragma unroll
        for (int w = 0; w < BLOCK / 64; ++w) {
            carry.x += s_wsum[w].x; carry.y += s_wsum[w].y;
            carry.z += s_wsum[w].z; carry.w += s_wsum[w].w;
        }
        // no barrier needed here: s_obs0 rewrite is fenced by (B),
        // s_wsum rewrite by next tile's (A)
    }

    if (t == 0) Yr[0] = make_float4(soc, soc, soc, soc);
}

extern "C" void kernel_launch(void* const* d_in, const int* in_sizes, int n_in,
                              void* d_out, int out_size, void* d_ws, size_t ws_size,
                              hipStream_t stream) {
    const float4* X  = (const float4*)d_in[0];
    const float* SC  = (const float*)d_in[1];
    const float* wi1 = (const float*)d_in[2];
    const float* bi1 = (const float*)d_in[3];
    const float* wi2 = (const float*)d_in[4];
    const float* bi2 = (const float*)d_in[5];
    const float* we1 = (const float*)d_in[6];
    const float* be1 = (const float*)d_in[7];
    const float* we2 = (const float*)d_in[8];
    const float* be2 = (const float*)d_in[9];
    float4* Y = (float4*)d_out;

    const int N = in_sizes[1] / 4;           // SC is (N,4)
    const int L = in_sizes[0] / (4 * N);     // X is (N,L,4)

    socnet_kernel<<<N, BLOCK, 0, stream>>>(X, SC, wi1, bi1, wi2, bi2,
                                           we1, be1, we2, be2, Y, L);
}

// Round 3
// 106.625 us; speedup vs baseline: 1.2237x; 1.2237x over previous
//
#include <hip/hip_runtime.h>
#include <math.h>

#define BLOCK 256
#define NW (BLOCK / 64)

typedef float f32x4 __attribute__((ext_vector_type(4)));

__device__ __forceinline__ float sp(float x) {
    // softplus: max(x,0) + log(1 + exp(-|x|)) — fast intrinsics, error budget is huge
    return fmaxf(x, 0.0f) + __logf(1.0f + __expf(-fabsf(x)));
}

__global__ __launch_bounds__(BLOCK) void socnet_kernel(
    const f32x4* __restrict__ X,      // (N, L) of 4-ch float4
    const float*  __restrict__ SC,    // (N, 4)
    const float*  __restrict__ wi1, const float* __restrict__ bi1,
    const float*  __restrict__ wi2, const float* __restrict__ bi2,
    const float*  __restrict__ we1, const float* __restrict__ be1,
    const float*  __restrict__ we2, const float* __restrict__ be2,
    f32x4* __restrict__ Y, int L)
{
    const int n    = blockIdx.x;
    const int t    = threadIdx.x;
    const int lane = t & 63;
    const int wid  = t >> 6;

    const size_t rowoff = (size_t)n * (size_t)L;
    const f32x4* Xr = X + rowoff;
    f32x4*       Yr = Y + rowoff;

    // eta MLP weights (broadcast scalars)
    const float W10 = we1[0], W11 = we1[1], B1 = be1[0];
    const float W2  = we2[0], B2e = be2[0];

    // per-row scalars
    const float Q    = SC[n * 4 + 0];
    const float eta0 = SC[n * 4 + 1];
    const float R    = SC[n * 4 + 2];
    const float S3   = SC[n * 4 + 3];
    const float inv  = eta0 / (3600.0f * Q);

    // soc_init from X[n,0,:] — all threads redundantly (cached load)
    const f32x4 x0 = Xr[0];
    const float h0 = sp(wi1[0] * x0.y + wi1[1] * x0.z + wi1[2] * x0.w + wi1[3] * R + bi1[0]);
    const float soc = S3 * (1.0f + (wi2[0] * h0 + bi2[0]));

    __shared__ f32x4 s_wsum[2][NW];  // double-buffered per-wave scan totals

    f32x4 carry = (f32x4)(0.0f);

    const int ntiles = L / BLOCK;  // 16
    for (int tile = 0; tile < ntiles; ++tile) {
        const int p  = tile * BLOCK + t;
        const int pn = (p + 1 < L) ? (p + 1) : p;  // clamp -> inc=0 at l=L-1 (unused)

        // Perfectly coalesced: lane-contiguous 16B. Second load is an L1 hit.
        const f32x4 xc = Xr[p];
        const f32x4 xn = Xr[pn];

        // delta_eta at p and p+1 (recompute neighbor; transcendentals are cheap)
        const float de_c = W2 * sp(W10 * xc.y + W11 * xc.z + B1) + B2e;
        const float de_n = W2 * sp(W10 * xn.y + W11 * xn.z + B1) + B2e;
        const float dy   = inv * (1.0f + de_c) * xc.y;

        // inc[p] = (obs[p+1] - obs[p]) * dy;  obs = (I, T, U, delta_eta)
        f32x4 inc;
        inc.x = (xn.y - xc.y) * dy;
        inc.y = (xn.z - xc.z) * dy;
        inc.z = (xn.w - xc.w) * dy;
        inc.w = (de_n - de_c) * dy;

        // 64-lane inclusive scan (4 channels)
        f32x4 scn = inc;
        #pragma unroll
        for (int off = 1; off < 64; off <<= 1) {
            const float ox = __shfl_up(scn.x, off);
            const float oy = __shfl_up(scn.y, off);
            const float oz = __shfl_up(scn.z, off);
            const float ow = __shfl_up(scn.w, off);
            if (lane >= off) { scn.x += ox; scn.y += oy; scn.z += oz; scn.w += ow; }
        }
        if (lane == 63) s_wsum[tile & 1][wid] = scn;
        __syncthreads();  // one barrier per tile (wsum double-buffered)

        // exclusive prefix at p = carry + prev-wave totals + (scn - inc)
        f32x4 excl = carry + scn - inc;
        #pragma unroll
        for (int w = 0; w < NW; ++w) {
            const f32x4 ws = s_wsum[tile & 1][w];
            if (w < wid) excl += ws;
            carry += ws;
        }

        // y[p] = soc + exclusive_prefix(p); aligned, coalesced, never re-read:
        // nontemporal so Y doesn't evict X from L3.
        const f32x4 yv = excl + (f32x4)(soc);
        __builtin_nontemporal_store(yv, &Yr[p]);
    }
}

extern "C" void kernel_launch(void* const* d_in, const int* in_sizes, int n_in,
                              void* d_out, int out_size, void* d_ws, size_t ws_size,
                              hipStream_t stream) {
    const f32x4* X   = (const f32x4*)d_in[0];
    const float* SC  = (const float*)d_in[1];
    const float* wi1 = (const float*)d_in[2];
    const float* bi1 = (const float*)d_in[3];
    const float* wi2 = (const float*)d_in[4];
    const float* bi2 = (const float*)d_in[5];
    const float* we1 = (const float*)d_in[6];
    const float* be1 = (const float*)d_in[7];
    const float* we2 = (const float*)d_in[8];
    const float* be2 = (const float*)d_in[9];
    f32x4* Y = (f32x4*)d_out;

    const int N = in_sizes[1] / 4;           // SC is (N,4)
    const int L = in_sizes[0] / (4 * N);     // X is (N,L,4)

    socnet_kernel<<<N, BLOCK, 0, stream>>>(X, SC, wi1, bi1, wi2, bi2,
                                           we1, be1, we2, be2, Y, L);
}

// Round 4
// 103.581 us; speedup vs baseline: 1.2597x; 1.0294x over previous
//
#include <hip/hip_runtime.h>
#include <math.h>

#define BLOCK 256
#define NW (BLOCK / 64)

typedef float f32x4 __attribute__((ext_vector_type(4)));

__device__ __forceinline__ float sp(float x) {
    // softplus: max(x,0) + log(1 + exp(-|x|)) — fast intrinsics, error budget is huge
    return fmaxf(x, 0.0f) + __logf(1.0f + __expf(-fabsf(x)));
}

__global__ __launch_bounds__(BLOCK) void socnet_kernel(
    const f32x4* __restrict__ X,      // (N, L) of 4-ch float4
    const float*  __restrict__ SC,    // (N, 4)
    const float*  __restrict__ wi1, const float* __restrict__ bi1,
    const float*  __restrict__ wi2, const float* __restrict__ bi2,
    const float*  __restrict__ we1, const float* __restrict__ be1,
    const float*  __restrict__ we2, const float* __restrict__ be2,
    f32x4* __restrict__ Y, int L)
{
    const int n    = blockIdx.x;
    const int t    = threadIdx.x;
    const int lane = t & 63;
    const int wid  = t >> 6;

    const size_t rowoff = (size_t)n * (size_t)L;
    const f32x4* Xr = X + rowoff;
    f32x4*       Yr = Y + rowoff;

    // eta MLP weights (broadcast scalars)
    const float W10 = we1[0], W11 = we1[1], B1 = be1[0];
    const float W2  = we2[0], B2e = be2[0];

    // per-row scalars
    const float Q    = SC[n * 4 + 0];
    const float eta0 = SC[n * 4 + 1];
    const float R    = SC[n * 4 + 2];
    const float S3   = SC[n * 4 + 3];
    const float inv  = eta0 / (3600.0f * Q);

    // soc_init from X[n,0,:] — all threads redundantly (cached load)
    const f32x4 x0 = Xr[0];
    const float h0 = sp(wi1[0] * x0.y + wi1[1] * x0.z + wi1[2] * x0.w + wi1[3] * R + bi1[0]);
    const float soc = S3 * (1.0f + (wi2[0] * h0 + bi2[0]));

    __shared__ f32x4 s_wsum[2][NW];  // double-buffered per-wave scan totals

    f32x4 carry = (f32x4)(0.0f);

    const int ntiles = L / BLOCK;  // 16
    const int Lm1 = L - 1;

    // ---- software pipeline: registers hold tile k's data before tile k runs ----
    int p = t;
    f32x4 xc = Xr[p];
    f32x4 xn = Xr[(p + 1 < L) ? (p + 1) : Lm1];

    for (int tile = 0; tile < ntiles; ++tile) {
        // Issue NEXT tile's loads now — their ~900-cycle HBM latency overlaps
        // this tile's softplus + scan + barrier instead of serializing after it.
        const int pnc = (p + BLOCK < L) ? (p + BLOCK) : Lm1;       // clamped (last iter: broadcast)
        const int pnn = (p + BLOCK + 1 < L) ? (p + BLOCK + 1) : Lm1;
        const f32x4 xc2 = Xr[pnc];
        const f32x4 xn2 = Xr[pnn];

        // delta_eta at p and p+1 (recompute neighbor; transcendentals are cheap)
        const float de_c = W2 * sp(W10 * xc.y + W11 * xc.z + B1) + B2e;
        const float de_n = W2 * sp(W10 * xn.y + W11 * xn.z + B1) + B2e;
        const float dy   = inv * (1.0f + de_c) * xc.y;

        // inc[p] = (obs[p+1] - obs[p]) * dy;  obs = (I, T, U, delta_eta)
        f32x4 inc;
        inc.x = (xn.y - xc.y) * dy;
        inc.y = (xn.z - xc.z) * dy;
        inc.z = (xn.w - xc.w) * dy;
        inc.w = (de_n - de_c) * dy;

        // 64-lane inclusive scan (4 channels)
        f32x4 scn = inc;
        #pragma unroll
        for (int off = 1; off < 64; off <<= 1) {
            const float ox = __shfl_up(scn.x, off);
            const float oy = __shfl_up(scn.y, off);
            const float oz = __shfl_up(scn.z, off);
            const float ow = __shfl_up(scn.w, off);
            if (lane >= off) { scn.x += ox; scn.y += oy; scn.z += oz; scn.w += ow; }
        }
        if (lane == 63) s_wsum[tile & 1][wid] = scn;
        __syncthreads();  // one barrier per tile (wsum double-buffered)

        // exclusive prefix at p = carry + prev-wave totals + (scn - inc)
        f32x4 excl = carry + scn - inc;
        #pragma unroll
        for (int w = 0; w < NW; ++w) {
            const f32x4 ws = s_wsum[tile & 1][w];
            if (w < wid) excl += ws;
            carry += ws;
        }

        // y[p] = soc + exclusive_prefix(p); aligned, coalesced, never re-read.
        const f32x4 yv = excl + (f32x4)(soc);
        __builtin_nontemporal_store(yv, &Yr[p]);

        // rotate the pipeline registers
        xc = xc2;
        xn = xn2;
        p += BLOCK;
    }
}

extern "C" void kernel_launch(void* const* d_in, const int* in_sizes, int n_in,
                              void* d_out, int out_size, void* d_ws, size_t ws_size,
                              hipStream_t stream) {
    const f32x4* X   = (const f32x4*)d_in[0];
    const float* SC  = (const float*)d_in[1];
    const float* wi1 = (const float*)d_in[2];
    const float* bi1 = (const float*)d_in[3];
    const float* wi2 = (const float*)d_in[4];
    const float* bi2 = (const float*)d_in[5];
    const float* we1 = (const float*)d_in[6];
    const float* be1 = (const float*)d_in[7];
    const float* we2 = (const float*)d_in[8];
    const float* be2 = (const float*)d_in[9];
    f32x4* Y = (f32x4*)d_out;

    const int N = in_sizes[1] / 4;           // SC is (N,4)
    const int L = in_sizes[0] / (4 * N);     // X is (N,L,4)

    socnet_kernel<<<N, BLOCK, 0, stream>>>(X, SC, wi1, bi1, wi2, bi2,
                                           we1, be1, we2, be2, Y, L);
}

// Round 6
// 95.718 us; speedup vs baseline: 1.3632x; 1.0822x over previous
//
#include <hip/hip_runtime.h>
#include <hip/hip_fp16.h>
#include <math.h>

#define BLOCK 256
#define NW (BLOCK / 64)

typedef float f32x4 __attribute__((ext_vector_type(4)));

union H2I { __half2 h; int i; };

__device__ __forceinline__ float sp(float x) {
    // softplus: max(x,0) + log(1 + exp(-|x|)) — fast intrinsics, error budget is huge
    return fmaxf(x, 0.0f) + __logf(1.0f + __expf(-fabsf(x)));
}

__global__ __launch_bounds__(BLOCK) void socnet_kernel(
    const f32x4* __restrict__ X,      // (N, L) of 4-ch float4
    const float*  __restrict__ SC,    // (N, 4)
    const float*  __restrict__ wi1, const float* __restrict__ bi1,
    const float*  __restrict__ wi2, const float* __restrict__ bi2,
    const float*  __restrict__ we1, const float* __restrict__ be1,
    const float*  __restrict__ we2, const float* __restrict__ be2,
    f32x4* __restrict__ Y, int L)
{
    const int n    = blockIdx.x;
    const int t    = threadIdx.x;
    const int lane = t & 63;
    const int wid  = t >> 6;

    const size_t rowoff = (size_t)n * (size_t)L;
    const f32x4* Xr = X + rowoff;
    f32x4*       Yr = Y + rowoff;

    // eta MLP weights (broadcast scalars)
    const float W10 = we1[0], W11 = we1[1], B1 = be1[0];
    const float W2  = we2[0], B2e = be2[0];

    // per-row scalars
    const float Q    = SC[n * 4 + 0];
    const float eta0 = SC[n * 4 + 1];
    const float R    = SC[n * 4 + 2];
    const float S3   = SC[n * 4 + 3];
    const float inv  = eta0 / (3600.0f * Q);

    // soc_init from X[n,0,:] — all threads redundantly (cached load)
    const f32x4 x0 = Xr[0];
    const float h0 = sp(wi1[0] * x0.y + wi1[1] * x0.z + wi1[2] * x0.w + wi1[3] * R + bi1[0]);
    const float soc = S3 * (1.0f + (wi2[0] * h0 + bi2[0]));

    __shared__ f32x4 s_wsum[2][NW];  // double-buffered per-wave scan totals (fp32)

    f32x4 carry = (f32x4)(0.0f);

    const int ntiles = L / BLOCK;  // 16
    const int Lm1 = L - 1;

    // software pipeline: registers hold tile k's data before tile k runs
    int p = t;
    f32x4 xc = Xr[p];
    f32x4 xn = Xr[(p + 1 < L) ? (p + 1) : Lm1];

    for (int tile = 0; tile < ntiles; ++tile) {
        // issue next tile's loads early (HBM latency overlaps scan+barrier)
        const int pnc = (p + BLOCK < L) ? (p + BLOCK) : Lm1;
        const int pnn = (p + BLOCK + 1 < L) ? (p + BLOCK + 1) : Lm1;
        const f32x4 xc2 = Xr[pnc];
        const f32x4 xn2 = Xr[pnn];

        // delta_eta at p and p+1
        const float de_c = W2 * sp(W10 * xc.y + W11 * xc.z + B1) + B2e;
        const float de_n = W2 * sp(W10 * xn.y + W11 * xn.z + B1) + B2e;
        const float dy   = inv * (1.0f + de_c) * xc.y;

        // inc[p] = (obs[p+1] - obs[p]) * dy;  obs = (I, T, U, delta_eta)
        f32x4 inc;
        inc.x = (xn.y - xc.y) * dy;
        inc.y = (xn.z - xc.z) * dy;
        inc.z = (xn.w - xc.w) * dy;
        inc.w = (de_n - de_c) * dy;

        // ---- 64-lane inclusive scan, 4 channels packed into 2× half2 ----
        // (halves the ds_bpermute count: 12 shfl instead of 24 per tile;
        //  inc ~2e-3 scale, tile prefix ~0.02 -> fp16 error ~1e-4 << 0.245 budget)
        H2I a, b;
        a.h = __floats2half2_rn(inc.x, inc.y);
        b.h = __floats2half2_rn(inc.z, inc.w);
        #pragma unroll
        for (int off = 1; off < 64; off <<= 1) {
            H2I ta, tb;
            ta.i = __shfl_up(a.i, off);
            tb.i = __shfl_up(b.i, off);
            if (lane >= off) { a.h = __hadd2(a.h, ta.h); b.h = __hadd2(b.h, tb.h); }
        }
        f32x4 scn;
        scn.x = __low2float(a.h);  scn.y = __high2float(a.h);
        scn.z = __low2float(b.h);  scn.w = __high2float(b.h);

        if (lane == 63) s_wsum[tile & 1][wid] = scn;
        __syncthreads();  // one barrier per tile (wsum double-buffered)

        // exclusive prefix at p = carry + prev-wave totals + (scn - inc)
        f32x4 excl = carry + scn - inc;
        #pragma unroll
        for (int w = 0; w < NW; ++w) {
            const f32x4 ws = s_wsum[tile & 1][w];
            if (w < wid) excl += ws;
            carry += ws;
        }

        // y[p] = soc + exclusive_prefix(p); coalesced nontemporal store
        const f32x4 yv = excl + (f32x4)(soc);
        __builtin_nontemporal_store(yv, &Yr[p]);

        // rotate pipeline registers
        xc = xc2;
        xn = xn2;
        p += BLOCK;
    }
}

extern "C" void kernel_launch(void* const* d_in, const int* in_sizes, int n_in,
                              void* d_out, int out_size, void* d_ws, size_t ws_size,
                              hipStream_t stream) {
    const f32x4* X   = (const f32x4*)d_in[0];
    const float* SC  = (const float*)d_in[1];
    const float* wi1 = (const float*)d_in[2];
    const float* bi1 = (const float*)d_in[3];
    const float* wi2 = (const float*)d_in[4];
    const float* bi2 = (const float*)d_in[5];
    const float* we1 = (const float*)d_in[6];
    const float* be1 = (const float*)d_in[7];
    const float* we2 = (const float*)d_in[8];
    const float* be2 = (const float*)d_in[9];
    f32x4* Y = (f32x4*)d_out;

    const int N = in_sizes[1] / 4;           // SC is (N,4)
    const int L = in_sizes[0] / (4 * N);     // X is (N,L,4)

    socnet_kernel<<<N, BLOCK, 0, stream>>>(X, SC, wi1, bi1, wi2, bi2,
                                           we1, be1, we2, be2, Y, L);
}

// Round 7
// 91.591 us; speedup vs baseline: 1.4246x; 1.0451x over previous
//
#include <hip/hip_runtime.h>
#include <math.h>

#define BLOCK 256
#define NW (BLOCK / 64)

typedef float f32x4 __attribute__((ext_vector_type(4)));

__device__ __forceinline__ float sp(float x) {
    // softplus: max(x,0) + log(1 + exp(-|x|)) — fast intrinsics, error budget is huge
    return fmaxf(x, 0.0f) + __logf(1.0f + __expf(-fabsf(x)));
}

// Wave64 inclusive scan (add) entirely on the VALU via DPP — no DS-pipe traffic.
// Classic GCN sequence (LLVM AMDGPUAtomicOptimizer::buildScan):
//   row_shr:1,2,4,8  -> per-16-lane-row inclusive scan
//   row_bcast:15 (rows 1,3) then row_bcast:31 (rows 2,3) -> stitch rows
__device__ __forceinline__ float wave_scan_f32(float s) {
    s += __int_as_float(__builtin_amdgcn_update_dpp(0, __float_as_int(s), 0x111, 0xf, 0xf, false));
    s += __int_as_float(__builtin_amdgcn_update_dpp(0, __float_as_int(s), 0x112, 0xf, 0xf, false));
    s += __int_as_float(__builtin_amdgcn_update_dpp(0, __float_as_int(s), 0x114, 0xf, 0xf, false));
    s += __int_as_float(__builtin_amdgcn_update_dpp(0, __float_as_int(s), 0x118, 0xf, 0xf, false));
    s += __int_as_float(__builtin_amdgcn_update_dpp(0, __float_as_int(s), 0x142, 0xa, 0xf, false));
    s += __int_as_float(__builtin_amdgcn_update_dpp(0, __float_as_int(s), 0x143, 0xc, 0xf, false));
    return s;
}

__global__ __launch_bounds__(BLOCK) void socnet_kernel(
    const f32x4* __restrict__ X,      // (N, L) of 4-ch float4
    const float*  __restrict__ SC,    // (N, 4)
    const float*  __restrict__ wi1, const float* __restrict__ bi1,
    const float*  __restrict__ wi2, const float* __restrict__ bi2,
    const float*  __restrict__ we1, const float* __restrict__ be1,
    const float*  __restrict__ we2, const float* __restrict__ be2,
    f32x4* __restrict__ Y, int L)
{
    const int n    = blockIdx.x;
    const int t    = threadIdx.x;
    const int wid  = t >> 6;

    const size_t rowoff = (size_t)n * (size_t)L;
    const f32x4* Xr = X + rowoff;
    f32x4*       Yr = Y + rowoff;

    // eta MLP weights (broadcast scalars)
    const float W10 = we1[0], W11 = we1[1], B1 = be1[0];
    const float W2  = we2[0], B2e = be2[0];

    // per-row scalars
    const float Q    = SC[n * 4 + 0];
    const float eta0 = SC[n * 4 + 1];
    const float R    = SC[n * 4 + 2];
    const float S3   = SC[n * 4 + 3];
    const float inv  = eta0 / (3600.0f * Q);

    // soc_init from X[n,0,:] — all threads redundantly (cached load)
    const f32x4 x0 = Xr[0];
    const float h0 = sp(wi1[0] * x0.y + wi1[1] * x0.z + wi1[2] * x0.w + wi1[3] * R + bi1[0]);
    const float soc = S3 * (1.0f + (wi2[0] * h0 + bi2[0]));

    __shared__ f32x4 s_wsum[2][NW];  // double-buffered per-wave scan totals

    f32x4 carry = (f32x4)(0.0f);

    const int ntiles = L / BLOCK;  // 16
    const int Lm1 = L - 1;

    // software pipeline: registers hold tile k's data before tile k runs
    int p = t;
    f32x4 xc = Xr[p];
    f32x4 xn = Xr[(p + 1 < L) ? (p + 1) : Lm1];

    for (int tile = 0; tile < ntiles; ++tile) {
        // issue next tile's loads early (HBM latency overlaps scan+barrier)
        const int pnc = (p + BLOCK < L) ? (p + BLOCK) : Lm1;
        const int pnn = (p + BLOCK + 1 < L) ? (p + BLOCK + 1) : Lm1;
        const f32x4 xc2 = Xr[pnc];
        const f32x4 xn2 = Xr[pnn];

        // delta_eta at p and p+1
        const float de_c = W2 * sp(W10 * xc.y + W11 * xc.z + B1) + B2e;
        const float de_n = W2 * sp(W10 * xn.y + W11 * xn.z + B1) + B2e;
        const float dy   = inv * (1.0f + de_c) * xc.y;

        // inc[p] = (obs[p+1] - obs[p]) * dy;  obs = (I, T, U, delta_eta)
        f32x4 inc;
        inc.x = (xn.y - xc.y) * dy;
        inc.y = (xn.z - xc.z) * dy;
        inc.z = (xn.w - xc.w) * dy;
        inc.w = (de_n - de_c) * dy;

        // ---- 64-lane inclusive scan, 4 fp32 channels, all on the VALU ----
        f32x4 scn;
        scn.x = wave_scan_f32(inc.x);
        scn.y = wave_scan_f32(inc.y);
        scn.z = wave_scan_f32(inc.z);
        scn.w = wave_scan_f32(inc.w);

        if ((t & 63) == 63) s_wsum[tile & 1][wid] = scn;
        __syncthreads();  // one barrier per tile (wsum double-buffered)

        // exclusive prefix at p = carry + prev-wave totals + (scn - inc)
        f32x4 excl = carry + scn - inc;
        #pragma unroll
        for (int w = 0; w < NW; ++w) {
            const f32x4 ws = s_wsum[tile & 1][w];
            if (w < wid) excl += ws;
            carry += ws;
        }

        // y[p] = soc + exclusive_prefix(p); coalesced nontemporal store
        const f32x4 yv = excl + (f32x4)(soc);
        __builtin_nontemporal_store(yv, &Yr[p]);

        // rotate pipeline registers
        xc = xc2;
        xn = xn2;
        p += BLOCK;
    }
}

extern "C" void kernel_launch(void* const* d_in, const int* in_sizes, int n_in,
                              void* d_out, int out_size, void* d_ws, size_t ws_size,
                              hipStream_t stream) {
    const f32x4* X   = (const f32x4*)d_in[0];
    const float* SC  = (const float*)d_in[1];
    const float* wi1 = (const float*)d_in[2];
    const float* bi1 = (const float*)d_in[3];
    const float* wi2 = (const float*)d_in[4];
    const float* bi2 = (const float*)d_in[5];
    const float* we1 = (const float*)d_in[6];
    const float* be1 = (const float*)d_in[7];
    const float* we2 = (const float*)d_in[8];
    const float* be2 = (const float*)d_in[9];
    f32x4* Y = (f32x4*)d_out;

    const int N = in_sizes[1] / 4;           // SC is (N,4)
    const int L = in_sizes[0] / (4 * N);     // X is (N,L,4)

    socnet_kernel<<<N, BLOCK, 0, stream>>>(X, SC, wi1, bi1, wi2, bi2,
                                           we1, be1, we2, be2, Y, L);
}